// Round 8
// baseline (4865.066 us; speedup 1.0000x reference)
//
#include <hip/hip_runtime.h>
#include <stdint.h>

// ---------- types / helpers ----------
typedef __attribute__((ext_vector_type(8))) short bf16x8;   // 8 bf16 in 4 VGPRs
typedef __attribute__((ext_vector_type(4))) float f32x4;

static __device__ __forceinline__ short f2bf(float f) {
  uint32_t u = __builtin_bit_cast(uint32_t, f);
  u += 0x7fffu + ((u >> 16) & 1u);          // round-to-nearest-even
  return (short)(u >> 16);
}

static __device__ __forceinline__ void gload_lds16(const void* g, void* l) {
  __builtin_amdgcn_global_load_lds((const __attribute__((address_space(1))) void*)g,
                                   (__attribute__((address_space(3))) void*)l, 16, 0, 0);
}

#define GFENCE asm volatile("" ::: "memory")

// ---------- x transpose: (B,C,T,H,W) f32 -> xb[n][c] bf16, n = b*16384 + p ----------
__global__ __launch_bounds__(256) void transpose_x_k(const float* __restrict__ x,
                                                     short* __restrict__ xb) {
  __shared__ float t[64][65];
  const int pt = blockIdx.x, ct = blockIdx.y, b = blockIdx.z;
  const int tid = threadIdx.x;
#pragma unroll
  for (int i = 0; i < 16; i++) {
    int cc = i * 4 + (tid >> 6);
    int pp = tid & 63;
    t[cc][pp] = x[(size_t)(b * 512 + ct * 64 + cc) * 16384 + pt * 64 + pp];
  }
  __syncthreads();
#pragma unroll
  for (int i = 0; i < 2; i++) {
    int seg = i * 256 + tid;
    int pw = seg >> 3, c8 = seg & 7;
    short tmp[8];
#pragma unroll
    for (int k = 0; k < 8; k++) tmp[k] = f2bf(t[c8 * 8 + k][pw]);
    *(uint4*)&xb[(size_t)(b * 16384 + pt * 64 + pw) * 512 + ct * 64 + c8 * 8] =
        *(const uint4*)tmp;
  }
}

// ---------- weight transpose+pack: (512x512 f32 [k][n]) -> fragment-major bf16 ----------
// unit (g, t, l) holds R[g*16 + (l&15)][t*32 + (l>>4)*8 .. +8] where R = src^T ([n][k]).
// dst unit offset = (nt*4+g')*gp + (t0 + kt*2+t')*64 + l   (unit = 8 shorts = 16 B)
struct WPtrs {
  const float* src[12];
  short* dst[12];
  int t0[12];   // k-tile offset within resident K
  int gp[12];   // group pitch in units (= NT_resident * 64)
};

__global__ __launch_bounds__(256) void transpose_pack_k(WPtrs P) {
  __shared__ float t[64][65];
  const int kt = blockIdx.x, nt = blockIdx.y, z = blockIdx.z;
  const float* src = P.src[z];
  short* dst = P.dst[z];
  const int tid = threadIdx.x;
#pragma unroll
  for (int i = 0; i < 16; i++) {
    int kk = i * 4 + (tid >> 6);
    int nn = tid & 63;
    t[kk][nn] = src[(size_t)(kt * 64 + kk) * 512 + nt * 64 + nn];
  }
  __syncthreads();
#pragma unroll
  for (int half = 0; half < 2; half++) {
    int u = half * 256 + tid;
    int gl = u >> 7;           // 0..3 local group
    int tp = (u >> 6) & 1;     // 0..1 local k-tile
    int l = u & 63;
    short tmp[8];
#pragma unroll
    for (int j = 0; j < 8; j++)
      tmp[j] = f2bf(t[tp * 32 + (l >> 4) * 8 + j][gl * 16 + (l & 15)]);
    size_t unit = (size_t)(nt * 4 + gl) * P.gp[z] +
                  (size_t)(P.t0[z] + kt * 2 + tp) * 64 + l;
    *(uint4*)&dst[unit * 8] = *(const uint4*)tmp;
  }
}

__global__ void bsum_k(const float* a, const float* b, const float* c, float* o) {
  int i = blockIdx.x * 256 + threadIdx.x;
  if (i < 512) o[i] = a[i] + b[i] + c[i];
}

// ---------- 128x128 GEMM, resident-operand-in-regs, 5 blocks/CU ----------
// Identical to round-7 structure; single change: __launch_bounds__(256,5) ->
// 5 blocks/CU (LDS 5x32 KiB = 160 KiB, VGPR cap 102 >= 80) for latency hiding.
// Streamed matrix S staged in LDS (4 bufs x 8 KB, stage depth 3, swizzled chunks,
// 0 bank conflicts). Resident matrix R read per K-tile as 4 coalesced
// global_load_dwordx4 from the packed frag-major buffer (rfA/rfB double-buffer,
// prefetched 1 tile ahead). vmcnt ledger: prologue wait 4, steady wait 2, tail 0,0.
// MODE 0 (QKV): streamed = A-side (xb rows), resident = B-side; D bf16 [M][ldd].
// MODE 1 (fc):  streamed = B-side (ob rows), resident = A-side; D f32 + bsum[c].
template <int MODE>
__global__ __launch_bounds__(256, 5) void gemm128r_k(const short* __restrict__ S,
                                                     int ldS,
                                                     const short* __restrict__ Rp,
                                                     void* __restrict__ Dp, int K,
                                                     int ldd,
                                                     const float* __restrict__ bsum,
                                                     int GN) {
  __shared__ char smem[32768];
  const int tid = threadIdx.x;
  const int lane = tid & 63, wave = tid >> 6;
  const int wm = (wave >> 1) << 6, wn = (wave & 1) << 6;
  const int r4 = lane & 15, kl = lane >> 4;

  // bijective XCD swizzle (gridDim.x % 8 == 0)
  int bid = blockIdx.x;
  const int cpx = gridDim.x >> 3;
  bid = (bid & 7) * cpx + (bid >> 3);
  int bm, bn;
  if constexpr (MODE == 0) {
    bn = bid % GN;
    bm = bid / GN;
  } else {
    bm = bid & 3;
    bn = bid >> 2;
  }

  const int NT = K >> 5;  // BK = 32; resident K == streamed K
  const int wS = (MODE == 0) ? wm : wn;   // streamed-side wave offset
  const int wR = (MODE == 0) ? wn : wm;   // resident-side wave offset
  const int bS = (MODE == 0) ? bm : bn;   // streamed tile idx
  const int bR = (MODE == 0) ? bn : bm;   // resident tile idx

  // streamed staging (swizzled global chunk, linear LDS dest)
  const int schk = (lane & 3) ^ ((lane >> 3) & 3);
  const short* gS0 =
      S + (size_t)(bS * 128 + wave * 32 + (lane >> 2)) * ldS + schk * 8;

  // resident packed bases (lane folded in); per-tile step = 512 shorts (1 KB)
  const int g0 = bR * 8 + (wR >> 4);
  const short* rb0 = Rp + ((size_t)(g0 + 0) * NT * 64 + lane) * 8;
  const short* rb1 = Rp + ((size_t)(g0 + 1) * NT * 64 + lane) * 8;
  const short* rb2 = Rp + ((size_t)(g0 + 2) * NT * 64 + lane) * 8;
  const short* rb3 = Rp + ((size_t)(g0 + 3) * NT * 64 + lane) * 8;

  // LDS fragment read offset (swizzle-consistent with staging)
  const int kls = kl ^ ((r4 >> 1) & 3);
  const int loff = (wS + r4) * 64 + kls * 16;

  f32x4 acc[4][4];
#pragma unroll
  for (int i = 0; i < 4; ++i)
#pragma unroll
    for (int j = 0; j < 4; ++j) acc[i][j] = (f32x4){0.f, 0.f, 0.f, 0.f};
  bf16x8 lf[4], rfA[4], rfB[4];

  auto stage = [&](int tt) {
    char* d = smem + (tt & 3) * 8192 + wave * 2048;
    gload_lds16(gS0 + (size_t)tt * 32, d);
    gload_lds16(gS0 + (size_t)16 * ldS + (size_t)tt * 32, d + 1024);
  };

#define MFMA_STEP(CUR)                                                         \
  do {                                                                         \
    __builtin_amdgcn_s_setprio(1);                                             \
    _Pragma("unroll") for (int mi = 0; mi < 4; ++mi)                           \
        _Pragma("unroll") for (int ni = 0; ni < 4; ++ni) {                     \
      if constexpr (MODE == 0)                                                 \
        acc[mi][ni] = __builtin_amdgcn_mfma_f32_16x16x32_bf16(                 \
            lf[mi], CUR[ni], acc[mi][ni], 0, 0, 0);                            \
      else                                                                     \
        acc[mi][ni] = __builtin_amdgcn_mfma_f32_16x16x32_bf16(                 \
            CUR[mi], lf[ni], acc[mi][ni], 0, 0, 0);                            \
    }                                                                          \
    __builtin_amdgcn_s_setprio(0);                                             \
  } while (0)

#define TILEV(tq, WAIT, CUR, NXT, DOSTAGE, DOPF)                               \
  do {                                                                         \
    asm volatile("s_waitcnt vmcnt(" WAIT ")" ::: "memory");                    \
    __builtin_amdgcn_s_barrier();                                              \
    GFENCE;                                                                    \
    if (DOPF) {                                                                \
      NXT[0] = *(const bf16x8*)(rb0 + ((tq) + 1) * 512);                       \
      NXT[1] = *(const bf16x8*)(rb1 + ((tq) + 1) * 512);                       \
      NXT[2] = *(const bf16x8*)(rb2 + ((tq) + 1) * 512);                       \
      NXT[3] = *(const bf16x8*)(rb3 + ((tq) + 1) * 512);                       \
    }                                                                          \
    GFENCE;                                                                    \
    {                                                                          \
      const char* bp = smem + ((tq) & 3) * 8192;                               \
      _Pragma("unroll") for (int i = 0; i < 4; ++i) lf[i] =                    \
          *(const bf16x8*)(bp + loff + i * 1024);                              \
    }                                                                          \
    MFMA_STEP(CUR);                                                            \
    GFENCE;                                                                    \
    __builtin_amdgcn_s_barrier();                                              \
    GFENCE;                                                                    \
    if (DOSTAGE) stage((tq) + 3);                                              \
  } while (0)

  // prologue (order matters for the vmcnt ledger): A0, rf0, A1, A2
  stage(0);
  GFENCE;
  rfA[0] = *(const bf16x8*)rb0;
  rfA[1] = *(const bf16x8*)rb1;
  rfA[2] = *(const bf16x8*)rb2;
  rfA[3] = *(const bf16x8*)rb3;
  GFENCE;
  stage(1);
  stage(2);

  TILEV(0, "4", rfA, rfB, 1, 1);
  TILEV(1, "2", rfB, rfA, 1, 1);
  for (int t = 2; t + 4 <= NT; t += 2) {
    TILEV(t, "2", rfA, rfB, 1, 1);
    TILEV(t + 1, "2", rfB, rfA, (t + 1 <= NT - 4), 1);
  }
  TILEV(NT - 2, "0", rfA, rfB, 0, 1);
  TILEV(NT - 1, "0", rfB, rfA, 0, 0);

#undef TILEV
#undef MFMA_STEP

  // ---- epilogue: C/D layout col=lane&15, row=kl*4+reg
  const int m0 = wm + kl * 4;
  const int n0 = wn + r4;
  if (MODE == 0) {
    short* D = (short*)Dp;
#pragma unroll
    for (int mi = 0; mi < 4; ++mi)
#pragma unroll
      for (int ni = 0; ni < 4; ++ni)
#pragma unroll
        for (int r = 0; r < 4; ++r) {
          int row = bm * 128 + m0 + mi * 16 + r;
          int col = bn * 128 + n0 + ni * 16;
          D[(size_t)row * ldd + col] = f2bf(acc[mi][ni][r]);
        }
  } else {
    float* D = (float*)Dp + (size_t)((bn * 128) >> 14) * 8388608;
#pragma unroll
    for (int mi = 0; mi < 4; ++mi)
#pragma unroll
      for (int ni = 0; ni < 4; ++ni)
#pragma unroll
        for (int r = 0; r < 4; ++r) {
          int c = bm * 128 + m0 + mi * 16 + r;          // channel (M dim)
          int n = (bn * 128 + n0 + ni * 16) & 16383;    // spatial within batch
          D[(size_t)c * 16384 + n] = acc[mi][ni][r] + bsum[c];
        }
  }
}

// ---------- axial attention: one block per (sequence, head) ----------
// qkv: [n][1536] bf16 (Q|K|V each 512); o: [n][ostride] bf16 at column obase
template <int L>
__global__ __launch_bounds__(256) void attn_k(const short* __restrict__ qkv,
                                              short* __restrict__ o, int Adiv, int Bmul,
                                              int Cmul, int stride, int obase,
                                              int ostride) {
  constexpr int R = 256 / L;          // threads per row
  constexpr int SPT = (L * L) / 256;  // scores per thread
  constexpr int OPT = 64 / R;         // outputs per thread
  __shared__ short Ks[L][72];
  __shared__ short Vs[L][72];
  __shared__ short Qs[L][72];
  __shared__ float att[L][L + 1];
  const int tid = threadIdx.x;
  const int blk = blockIdx.x;
  const int s = blk >> 3, head = blk & 7;
  const int base = (s / Adiv) * Bmul + (s % Adiv) * Cmul;

  for (int idx = tid; idx < L * 8 * 3; idx += 256) {
    int part = idx / (L * 8);
    int rem = idx - part * (L * 8);
    int row = rem >> 3, seg = rem & 7;
    int n = base + row * stride;
    uint4 v = *(const uint4*)&qkv[(size_t)n * 1536 + part * 512 + head * 64 + seg * 8];
    short* dst = (part == 0 ? &Qs[row][0] : part == 1 ? &Ks[row][0] : &Vs[row][0]);
    *(uint4*)(dst + seg * 8) = v;
  }
  __syncthreads();

  const int l = tid / R, r = tid % R;
  float q[64];
#pragma unroll
  for (int w = 0; w < 8; w++) {
    uint4 u = *(const uint4*)&Qs[l][w * 8];
    uint32_t arr[4] = {u.x, u.y, u.z, u.w};
#pragma unroll
    for (int p = 0; p < 4; p++) {
      q[w * 8 + p * 2] = __builtin_bit_cast(float, arr[p] << 16);
      q[w * 8 + p * 2 + 1] = __builtin_bit_cast(float, arr[p] & 0xffff0000u);
    }
  }
  float sc[SPT];
#pragma unroll
  for (int jj = 0; jj < SPT; jj++) {
    int j = jj * R + r;
    float a0 = 0.f;
#pragma unroll
    for (int w = 0; w < 8; w++) {
      uint4 u = *(const uint4*)&Ks[j][w * 8];
      uint32_t arr[4] = {u.x, u.y, u.z, u.w};
#pragma unroll
      for (int p = 0; p < 4; p++) {
        a0 += q[w * 8 + p * 2] * __builtin_bit_cast(float, arr[p] << 16);
        a0 += q[w * 8 + p * 2 + 1] * __builtin_bit_cast(float, arr[p] & 0xffff0000u);
      }
    }
    sc[jj] = a0 * 0.125f;  // 1/sqrt(64)
  }
  float mx = sc[0];
#pragma unroll
  for (int jj = 1; jj < SPT; jj++) mx = fmaxf(mx, sc[jj]);
#pragma unroll
  for (int d = 1; d < R; d <<= 1) mx = fmaxf(mx, __shfl_xor(mx, d));
  float p_[SPT];
  float sum = 0.f;
#pragma unroll
  for (int jj = 0; jj < SPT; jj++) {
    p_[jj] = __expf(sc[jj] - mx);
    sum += p_[jj];
  }
#pragma unroll
  for (int d = 1; d < R; d <<= 1) sum += __shfl_xor(sum, d);
  float inv = 1.0f / sum;
#pragma unroll
  for (int jj = 0; jj < SPT; jj++) att[l][jj * R + r] = p_[jj] * inv;
  __syncthreads();

  float oa[OPT] = {};
#pragma unroll 4
  for (int j = 0; j < L; j++) {
    float a = att[l][j];
    if constexpr (OPT == 8) {
      uint4 u = *(const uint4*)&Vs[j][r * 8];
      uint32_t arr[4] = {u.x, u.y, u.z, u.w};
#pragma unroll
      for (int p = 0; p < 4; p++) {
        oa[p * 2] += a * __builtin_bit_cast(float, arr[p] << 16);
        oa[p * 2 + 1] += a * __builtin_bit_cast(float, arr[p] & 0xffff0000u);
      }
    } else {
      uint2 u = *(const uint2*)&Vs[j][r * 4];
      uint32_t arr[2] = {u.x, u.y};
#pragma unroll
      for (int p = 0; p < 2; p++) {
        oa[p * 2] += a * __builtin_bit_cast(float, arr[p] << 16);
        oa[p * 2 + 1] += a * __builtin_bit_cast(float, arr[p] & 0xffff0000u);
      }
    }
  }
  short tmp[OPT];
#pragma unroll
  for (int i = 0; i < OPT; i++) tmp[i] = f2bf(oa[i]);
  int n = base + l * stride;
  if constexpr (OPT == 8)
    *(uint4*)&o[(size_t)n * ostride + obase + head * 64 + r * 8] = *(const uint4*)tmp;
  else
    *(uint2*)&o[(size_t)n * ostride + obase + head * 64 + r * 4] = *(const uint2*)tmp;
}

// ---------- launch ----------
extern "C" void kernel_launch(void* const* d_in, const int* in_sizes, int n_in,
                              void* d_out, int out_size, void* d_ws, size_t ws_size,
                              hipStream_t stream) {
  const float* x = (const float*)d_in[0];
  const float* wq[3];
  const float* wk[3];
  const float* wv[3];
  const float* fc[3];
  const float* fb[3];
  for (int a = 0; a < 3; a++) {
    wq[a] = (const float*)d_in[1 + a * 5];
    wk[a] = (const float*)d_in[2 + a * 5];
    wv[a] = (const float*)d_in[3 + a * 5];
    fc[a] = (const float*)d_in[4 + a * 5];
    fb[a] = (const float*)d_in[5 + a * 5];
  }
  char* ws = (char*)d_ws;
  short* xb = (short*)(ws);                      //  67,108,864 B
  short* qkv = (short*)(ws + 67108864);          // 201,326,592 B
  short* wqkvp = (short*)(ws + 268435456);       //   4,718,592 B (3 axes x 96 grp x 16 kt)
  short* fcp = (short*)(ws + 273154048);         //   1,572,864 B (32 grp x 48 kt)
  float* bsum = (float*)(ws + 274726912);        //       2,048 B
  short* ob = (short*)(ws + 274728960);          // 201,326,592 B (65536 x 1536)
  float* out = (float*)d_out;

  WPtrs P;
  for (int a = 0; a < 3; a++) {
    const float* srcs[4] = {wq[a], wk[a], wv[a], fc[a]};
    for (int w = 0; w < 4; w++) {
      int z = a * 4 + w;
      P.src[z] = srcs[w];
      if (w < 3) {
        P.dst[z] = wqkvp + ((size_t)a * 98304 + (size_t)w * 32768) * 8;
        P.t0[z] = 0;
        P.gp[z] = 1024;   // NT=16 * 64
      } else {
        P.dst[z] = fcp;
        P.t0[z] = a * 16;
        P.gp[z] = 3072;   // NT=48 * 64
      }
    }
  }
  transpose_pack_k<<<dim3(8, 8, 12), 256, 0, stream>>>(P);
  bsum_k<<<dim3(2), 256, 0, stream>>>(fb[0], fb[1], fb[2], bsum);
  transpose_x_k<<<dim3(256, 8, 4), 256, 0, stream>>>(x, xb);

  // per-axis attention geometry: base = (s/Adiv)*Bmul + (s%Adiv)*Cmul, rows step `stride`
  const int Ad[3] = {1, 32, 1024};
  const int Bm_[3] = {32, 1024, 16384};
  const int Cm[3] = {0, 1, 1};
  const int St[3] = {1, 32, 1024};
  const int Ls[3] = {32, 32, 16};

  for (int a = 0; a < 3; a++) {
    // QKV: M=65536 (512 bm tiles), N=1536 (12 bn tiles), K=512 (NT=16)
    gemm128r_k<0><<<dim3(6144), 256, 0, stream>>>(
        xb, 512, wqkvp + (size_t)a * 98304 * 8, (void*)qkv, 512, 1536, nullptr, 12);
    if (Ls[a] == 32)
      attn_k<32><<<dim3(2048 * 8), 256, 0, stream>>>(qkv, ob, Ad[a], Bm_[a], Cm[a],
                                                     St[a], a * 512, 1536);
    else
      attn_k<16><<<dim3(4096 * 8), 256, 0, stream>>>(qkv, ob, Ad[a], Bm_[a], Cm[a],
                                                     St[a], a * 512, 1536);
  }
  // fused fc: out[c][n] = sum_k ob[n][k] * fcp-frags[c][k] + bsum[c]
  // M=512 (4 resident tiles), N=65536 (512 streamed tiles), K=1536 (NT=48)
  gemm128r_k<1><<<dim3(2048), 256, 0, stream>>>(ob, 1536, fcp, (void*)out, 1536, 0,
                                                bsum, 0);
}

// Round 9
// 829.920 us; speedup vs baseline: 5.8621x; 5.8621x over previous
//
#include <hip/hip_runtime.h>
#include <stdint.h>

// ---------- types / helpers ----------
typedef __attribute__((ext_vector_type(8))) short bf16x8;   // 8 bf16 in 4 VGPRs
typedef __attribute__((ext_vector_type(4))) float f32x4;

static __device__ __forceinline__ short f2bf(float f) {
  uint32_t u = __builtin_bit_cast(uint32_t, f);
  u += 0x7fffu + ((u >> 16) & 1u);          // round-to-nearest-even
  return (short)(u >> 16);
}

static __device__ __forceinline__ void gload_lds16(const void* g, void* l) {
  __builtin_amdgcn_global_load_lds((const __attribute__((address_space(1))) void*)g,
                                   (__attribute__((address_space(3))) void*)l, 16, 0, 0);
}

#define GFENCE asm volatile("" ::: "memory")

// ---------- x transpose: (B,C,T,H,W) f32 -> xb[n][c] bf16, n = b*16384 + p ----------
__global__ __launch_bounds__(256) void transpose_x_k(const float* __restrict__ x,
                                                     short* __restrict__ xb) {
  __shared__ float t[64][65];
  const int pt = blockIdx.x, ct = blockIdx.y, b = blockIdx.z;
  const int tid = threadIdx.x;
#pragma unroll
  for (int i = 0; i < 16; i++) {
    int cc = i * 4 + (tid >> 6);
    int pp = tid & 63;
    t[cc][pp] = x[(size_t)(b * 512 + ct * 64 + cc) * 16384 + pt * 64 + pp];
  }
  __syncthreads();
#pragma unroll
  for (int i = 0; i < 2; i++) {
    int seg = i * 256 + tid;
    int pw = seg >> 3, c8 = seg & 7;
    short tmp[8];
#pragma unroll
    for (int k = 0; k < 8; k++) tmp[k] = f2bf(t[c8 * 8 + k][pw]);
    *(uint4*)&xb[(size_t)(b * 16384 + pt * 64 + pw) * 512 + ct * 64 + c8 * 8] =
        *(const uint4*)tmp;
  }
}

// ---------- weight transpose: 12x (512x512 f32 [k][n]) -> bf16 [n][k], per-dst ld ----------
struct WPtrs {
  const float* src[12];
  short* dst[12];
  int ld[12];
};

__global__ __launch_bounds__(256) void transpose_w_k(WPtrs P) {
  __shared__ float t[64][65];
  const int kt = blockIdx.x, nt = blockIdx.y, z = blockIdx.z;
  const float* src = P.src[z];
  short* dst = P.dst[z];
  const int ld = P.ld[z];
  const int tid = threadIdx.x;
#pragma unroll
  for (int i = 0; i < 16; i++) {
    int kk = i * 4 + (tid >> 6);
    int nn = tid & 63;
    t[kk][nn] = src[(kt * 64 + kk) * 512 + nt * 64 + nn];
  }
  __syncthreads();
#pragma unroll
  for (int i = 0; i < 2; i++) {
    int seg = i * 256 + tid;
    int nn = seg >> 3, k8 = seg & 7;
    short tmp[8];
#pragma unroll
    for (int k = 0; k < 8; k++) tmp[k] = f2bf(t[k8 * 8 + k][nn]);
    *(uint4*)&dst[(size_t)(nt * 64 + nn) * ld + kt * 64 + k8 * 8] = *(const uint4*)tmp;
  }
}

__global__ void bsum_k(const float* a, const float* b, const float* c, float* o) {
  int i = blockIdx.x * 256 + threadIdx.x;
  if (i < 512) o[i] = a[i] + b[i] + c[i];
}

// ---------- 256x256 8-phase GEMM: D = A(MxK, lda) * B(NxK, ldb)^T, bf16 in ----------
// (round-4 proven best: 831 us total)
// LDS: 2 buffers x {ALO, AHI, BLO, BHI}, each K-half = 256 rows x 32 k x 2B = 16 KB.
// XOR swizzle within 1 KiB subtile: read kl ^= r4>>2; stage global chunk ^= (tid>>4)&3.
// Phases per K-tile t: P0(kh0,mq0) P1(kh0,mq1) P2(kh1,mq0) P3(kh1,mq1).
// Stage stream: P0:AHI(t+1) P1:BHI(t+1) P2:ALO(t+2) P3:BLO(t+2).
// Waits: vmcnt(8) @P0 and @P2 (12 outstanding, retire current tile's halves).
// Tail: peel NT-2 (hi stages only, 8/8) and NT-1 (no stages, 4/0).
// MODE 0: D bf16 [M][ldd].  MODE 1: D f32 out (B,C,THW) = v + bsum[c].  MODE 2: D += v.
#define LOADB(b, kh)                                                           \
  do {                                                                         \
    _Pragma("unroll") for (int ni = 0; ni < 4; ++ni) bfr[ni] =                 \
        *(const bf16x8*)(smem + ((b) * 4 + 2 + (kh)) * 16384 + boff +          \
                         ni * 1024);                                           \
  } while (0)

#define LOADA(b, kh, mq)                                                       \
  do {                                                                         \
    _Pragma("unroll") for (int mi = 0; mi < 4; ++mi) af[mi] =                  \
        *(const bf16x8*)(smem + ((b) * 4 + (kh)) * 16384 + aoff +              \
                         ((mq) * 4 + mi) * 1024);                              \
  } while (0)

#define MFMA16(mq)                                                             \
  do {                                                                         \
    __builtin_amdgcn_s_setprio(1);                                             \
    _Pragma("unroll") for (int mi = 0; mi < 4; ++mi)                           \
        _Pragma("unroll") for (int ni = 0; ni < 4; ++ni) acc[(mq) * 4 + mi]    \
            [ni] = __builtin_amdgcn_mfma_f32_16x16x32_bf16(                    \
                af[mi], bfr[ni], acc[(mq) * 4 + mi][ni], 0, 0, 0);             \
    __builtin_amdgcn_s_setprio(0);                                             \
    GFENCE;                                                                    \
  } while (0)

#define TILE(b, W0, W2, S0, S1, S2, S3)                                        \
  do {                                                                         \
    asm volatile("s_waitcnt vmcnt(" W0 ")" ::: "memory");                      \
    __builtin_amdgcn_s_barrier();                                              \
    GFENCE;                                                                    \
    LOADB(b, 0);                                                               \
    LOADA(b, 0, 0);                                                            \
    S0;                                                                        \
    MFMA16(0);                                                                 \
    __builtin_amdgcn_s_barrier();                                              \
    GFENCE;                                                                    \
    LOADA(b, 0, 1);                                                            \
    S1;                                                                        \
    MFMA16(1);                                                                 \
    asm volatile("s_waitcnt vmcnt(" W2 ")" ::: "memory");                      \
    __builtin_amdgcn_s_barrier();                                              \
    GFENCE;                                                                    \
    LOADB(b, 1);                                                               \
    LOADA(b, 1, 0);                                                            \
    S2;                                                                        \
    MFMA16(0);                                                                 \
    __builtin_amdgcn_s_barrier();                                              \
    GFENCE;                                                                    \
    LOADA(b, 1, 1);                                                            \
    S3;                                                                        \
    MFMA16(1);                                                                 \
  } while (0)

template <int MODE>
__global__ __launch_bounds__(512, 2) void gemm256_k(const short* __restrict__ A,
                                                    int lda,
                                                    const short* __restrict__ B,
                                                    int ldb, void* __restrict__ Dp,
                                                    int K, int ldd,
                                                    const float* __restrict__ bsum,
                                                    int GN) {
  extern __shared__ char smem[];
  const int tid = threadIdx.x;
  const int lane = tid & 63, wave = tid >> 6;
  const int wr = wave >> 2, wc = wave & 3;
  const int r4 = lane & 15, kl = lane >> 4;

  // bijective XCD swizzle (gridDim.x % 8 == 0 for all our grids)
  int bid = blockIdx.x;
  const int cpx = gridDim.x >> 3;
  bid = (bid & 7) * cpx + (bid >> 3);
  int bm, bn;
  if constexpr (MODE == 0) {
    bn = bid % GN;
    bm = bid / GN;
  } else {
    bm = bid & 1;
    bn = bid >> 1;
  }

  const int NT = K >> 6;

  // staging: per thread row/chunk; chunk pre-swizzled (involution) so linear
  // LDS dest + swizzled read are consistent.
  const int srow = tid >> 2;                       // 0..127 (instr i adds 128)
  const int schk = (tid & 3) ^ ((tid >> 4) & 3);   // swizzled 16B chunk
  const short* gA0 = A + (size_t)(bm * 256 + srow) * lda + schk * 8;
  const short* gB0 = B + (size_t)(bn * 256 + srow) * ldb + schk * 8;

  auto stage = [&](int tt, int x) {  // x: 0 ALO, 1 AHI, 2 BLO, 3 BHI
    const short* g = (x < 2) ? gA0 : gB0;
    const size_t rstep = (size_t)128 * ((x < 2) ? lda : ldb);
    const size_t koff = (size_t)tt * 64 + (x & 1) * 32;
    char* ldst = smem + (((tt & 1) * 4 + x) * 16384) + wave * 1024;
#pragma unroll
    for (int i = 0; i < 2; ++i)
      gload_lds16(g + i * rstep + koff, ldst + i * 8192);
  };

  // fragment read offsets (swizzled: kl ^= r4>>2 within the 1 KiB subtile)
  const int kls = kl ^ (r4 >> 2);
  const int aoff = wr * 8192 + r4 * 64 + kls * 16;
  const int boff = wc * 4096 + r4 * 64 + kls * 16;

  f32x4 acc[8][4];
#pragma unroll
  for (int i = 0; i < 8; ++i)
#pragma unroll
    for (int j = 0; j < 4; ++j) acc[i][j] = (f32x4){0.f, 0.f, 0.f, 0.f};
  bf16x8 af[4], bfr[4];

  // prologue: ALO0 BLO0 AHI0 BHI0 ALO1 BLO1  (12 loads/thread in flight)
  stage(0, 0);
  stage(0, 2);
  stage(0, 1);
  stage(0, 3);
  stage(1, 0);
  stage(1, 2);

  int t = 0;
  for (; t < NT - 2; ++t) {
    const int b = t & 1;
    TILE(b, "8", "8", stage(t + 1, 1), stage(t + 1, 3), stage(t + 2, 0),
         stage(t + 2, 2));
  }
  {
    const int b = t & 1;  // t == NT-2: stage hi of last tile only
    TILE(b, "8", "8", stage(t + 1, 1), stage(t + 1, 3), (void)0, (void)0);
    ++t;
  }
  {
    const int b = t & 1;  // t == NT-1: nothing left to stage
    TILE(b, "4", "0", (void)0, (void)0, (void)0, (void)0);
  }

  // ---- epilogue
  const int m0 = wr * 128 + kl * 4;
  const int n0 = wc * 64 + r4;
  if (MODE == 0) {
    short* D = (short*)Dp;
#pragma unroll
    for (int mi = 0; mi < 8; ++mi)
#pragma unroll
      for (int ni = 0; ni < 4; ++ni)
#pragma unroll
        for (int r = 0; r < 4; ++r) {
          int row = bm * 256 + m0 + mi * 16 + r;
          int col = bn * 256 + n0 + ni * 16;
          D[(size_t)row * ldd + col] = f2bf(acc[mi][ni][r]);
        }
  } else {
    float* D = (float*)Dp + (size_t)((bn * 256) >> 14) * 8388608;
#pragma unroll
    for (int mi = 0; mi < 8; ++mi)
#pragma unroll
      for (int ni = 0; ni < 4; ++ni)
#pragma unroll
        for (int r = 0; r < 4; ++r) {
          int c = bm * 256 + m0 + mi * 16 + r;          // channel (M dim)
          int n = (bn * 256 + n0 + ni * 16) & 16383;    // spatial within batch
          if (MODE == 1)
            D[(size_t)c * 16384 + n] = acc[mi][ni][r] + bsum[c];
          else
            D[(size_t)c * 16384 + n] += acc[mi][ni][r];
        }
  }
}

// ---------- axial attention: one block per (sequence, head) ----------
// qkv: [n][1536] bf16 (Q|K|V each 512); o: [n][ostride] bf16 at column obase
template <int L>
__global__ __launch_bounds__(256) void attn_k(const short* __restrict__ qkv,
                                              short* __restrict__ o, int Adiv, int Bmul,
                                              int Cmul, int stride, int obase,
                                              int ostride) {
  constexpr int R = 256 / L;          // threads per row
  constexpr int SPT = (L * L) / 256;  // scores per thread
  constexpr int OPT = 64 / R;         // outputs per thread
  __shared__ short Ks[L][72];
  __shared__ short Vs[L][72];
  __shared__ short Qs[L][72];
  __shared__ float att[L][L + 1];
  const int tid = threadIdx.x;
  const int blk = blockIdx.x;
  const int s = blk >> 3, head = blk & 7;
  const int base = (s / Adiv) * Bmul + (s % Adiv) * Cmul;

  for (int idx = tid; idx < L * 8 * 3; idx += 256) {
    int part = idx / (L * 8);
    int rem = idx - part * (L * 8);
    int row = rem >> 3, seg = rem & 7;
    int n = base + row * stride;
    uint4 v = *(const uint4*)&qkv[(size_t)n * 1536 + part * 512 + head * 64 + seg * 8];
    short* dst = (part == 0 ? &Qs[row][0] : part == 1 ? &Ks[row][0] : &Vs[row][0]);
    *(uint4*)(dst + seg * 8) = v;
  }
  __syncthreads();

  const int l = tid / R, r = tid % R;
  float q[64];
#pragma unroll
  for (int w = 0; w < 8; w++) {
    uint4 u = *(const uint4*)&Qs[l][w * 8];
    uint32_t arr[4] = {u.x, u.y, u.z, u.w};
#pragma unroll
    for (int p = 0; p < 4; p++) {
      q[w * 8 + p * 2] = __builtin_bit_cast(float, arr[p] << 16);
      q[w * 8 + p * 2 + 1] = __builtin_bit_cast(float, arr[p] & 0xffff0000u);
    }
  }
  float sc[SPT];
#pragma unroll
  for (int jj = 0; jj < SPT; jj++) {
    int j = jj * R + r;
    float a0 = 0.f;
#pragma unroll
    for (int w = 0; w < 8; w++) {
      uint4 u = *(const uint4*)&Ks[j][w * 8];
      uint32_t arr[4] = {u.x, u.y, u.z, u.w};
#pragma unroll
      for (int p = 0; p < 4; p++) {
        a0 += q[w * 8 + p * 2] * __builtin_bit_cast(float, arr[p] << 16);
        a0 += q[w * 8 + p * 2 + 1] * __builtin_bit_cast(float, arr[p] & 0xffff0000u);
      }
    }
    sc[jj] = a0 * 0.125f;  // 1/sqrt(64)
  }
  float mx = sc[0];
#pragma unroll
  for (int jj = 1; jj < SPT; jj++) mx = fmaxf(mx, sc[jj]);
#pragma unroll
  for (int d = 1; d < R; d <<= 1) mx = fmaxf(mx, __shfl_xor(mx, d));
  float p_[SPT];
  float sum = 0.f;
#pragma unroll
  for (int jj = 0; jj < SPT; jj++) {
    p_[jj] = __expf(sc[jj] - mx);
    sum += p_[jj];
  }
#pragma unroll
  for (int d = 1; d < R; d <<= 1) sum += __shfl_xor(sum, d);
  float inv = 1.0f / sum;
#pragma unroll
  for (int jj = 0; jj < SPT; jj++) att[l][jj * R + r] = p_[jj] * inv;
  __syncthreads();

  float oa[OPT] = {};
#pragma unroll 4
  for (int j = 0; j < L; j++) {
    float a = att[l][j];
    if constexpr (OPT == 8) {
      uint4 u = *(const uint4*)&Vs[j][r * 8];
      uint32_t arr[4] = {u.x, u.y, u.z, u.w};
#pragma unroll
      for (int p = 0; p < 4; p++) {
        oa[p * 2] += a * __builtin_bit_cast(float, arr[p] << 16);
        oa[p * 2 + 1] += a * __builtin_bit_cast(float, arr[p] & 0xffff0000u);
      }
    } else {
      uint2 u = *(const uint2*)&Vs[j][r * 4];
      uint32_t arr[2] = {u.x, u.y};
#pragma unroll
      for (int p = 0; p < 2; p++) {
        oa[p * 2] += a * __builtin_bit_cast(float, arr[p] << 16);
        oa[p * 2 + 1] += a * __builtin_bit_cast(float, arr[p] & 0xffff0000u);
      }
    }
  }
  short tmp[OPT];
#pragma unroll
  for (int i = 0; i < OPT; i++) tmp[i] = f2bf(oa[i]);
  int n = base + l * stride;
  if constexpr (OPT == 8)
    *(uint4*)&o[(size_t)n * ostride + obase + head * 64 + r * 8] = *(const uint4*)tmp;
  else
    *(uint2*)&o[(size_t)n * ostride + obase + head * 64 + r * 4] = *(const uint2*)tmp;
}

// ---------- launch ----------
extern "C" void kernel_launch(void* const* d_in, const int* in_sizes, int n_in,
                              void* d_out, int out_size, void* d_ws, size_t ws_size,
                              hipStream_t stream) {
  const float* x = (const float*)d_in[0];
  const float* wq[3];
  const float* wk[3];
  const float* wv[3];
  const float* fc[3];
  const float* fb[3];
  for (int a = 0; a < 3; a++) {
    wq[a] = (const float*)d_in[1 + a * 5];
    wk[a] = (const float*)d_in[2 + a * 5];
    wv[a] = (const float*)d_in[3 + a * 5];
    fc[a] = (const float*)d_in[4 + a * 5];
    fb[a] = (const float*)d_in[5 + a * 5];
  }
  char* ws = (char*)d_ws;
  short* xb = (short*)(ws);                      //  67,108,864 B
  short* qkv = (short*)(ws + 67108864);          // 201,326,592 B
  short* wqkvt = (short*)(ws + 268435456);       //   4,718,592 B (3 x 1536x512)
  short* fctA = (short*)(ws + 273154048);        //   1,572,864 B (512 x 1536)
  float* bsum = (float*)(ws + 274726912);        //       2,048 B
  short* ob = (short*)(ws + 274728960);          // 67 MB (fallback) / 201 MB (fused)
  float* out = (float*)d_out;

  // fused fc path needs ob_all = 65536x1536 bf16 -> total 476,055,552 B
  const bool fused = ws_size >= 476055552ull;

  // allow 128 KiB dynamic LDS (host-side, capture-safe)
  (void)hipFuncSetAttribute((const void*)&gemm256_k<0>,
                            hipFuncAttributeMaxDynamicSharedMemorySize, 131072);
  (void)hipFuncSetAttribute((const void*)&gemm256_k<1>,
                            hipFuncAttributeMaxDynamicSharedMemorySize, 131072);
  (void)hipFuncSetAttribute((const void*)&gemm256_k<2>,
                            hipFuncAttributeMaxDynamicSharedMemorySize, 131072);

  WPtrs P;
  for (int a = 0; a < 3; a++) {
    P.src[a * 4 + 0] = wq[a];
    P.src[a * 4 + 1] = wk[a];
    P.src[a * 4 + 2] = wv[a];
    P.src[a * 4 + 3] = fc[a];
    P.dst[a * 4 + 0] = wqkvt + (size_t)a * 1536 * 512;
    P.dst[a * 4 + 1] = wqkvt + (size_t)a * 1536 * 512 + 512 * 512;
    P.dst[a * 4 + 2] = wqkvt + (size_t)a * 1536 * 512 + 2 * 512 * 512;
    P.dst[a * 4 + 3] = fctA + a * 512;   // packed [c][a*512 + k], ld 1536
    P.ld[a * 4 + 0] = 512;
    P.ld[a * 4 + 1] = 512;
    P.ld[a * 4 + 2] = 512;
    P.ld[a * 4 + 3] = 1536;
  }
  transpose_w_k<<<dim3(8, 8, 12), 256, 0, stream>>>(P);
  bsum_k<<<dim3(2), 256, 0, stream>>>(fb[0], fb[1], fb[2], bsum);
  transpose_x_k<<<dim3(256, 8, 4), 256, 0, stream>>>(x, xb);

  // per-axis attention geometry: base = (s/Adiv)*Bmul + (s%Adiv)*Cmul, rows step `stride`
  const int Ad[3] = {1, 32, 1024};
  const int Bm_[3] = {32, 1024, 16384};
  const int Cm[3] = {0, 1, 1};
  const int St[3] = {1, 32, 1024};
  const int Ls[3] = {32, 32, 16};

  for (int a = 0; a < 3; a++) {
    // QKV: M=65536 (256 bm tiles), N=1536 (6 bn tiles), K=512
    gemm256_k<0><<<dim3(1536), 512, 131072, stream>>>(
        xb, 512, wqkvt + (size_t)a * 1536 * 512, 512, (void*)qkv, 512, 1536,
        nullptr, 6);
    const int obase = fused ? a * 512 : 0;
    const int ostr = fused ? 1536 : 512;
    if (Ls[a] == 32)
      attn_k<32><<<dim3(2048 * 8), 256, 0, stream>>>(qkv, ob, Ad[a], Bm_[a], Cm[a],
                                                     St[a], obase, ostr);
    else
      attn_k<16><<<dim3(4096 * 8), 256, 0, stream>>>(qkv, ob, Ad[a], Bm_[a], Cm[a],
                                                     St[a], obase, ostr);
    if (!fused) {
      // per-axis fc: M=512 (2 bm), N=65536 (256 bn), K=512 (A k-window a*512)
      if (a == 0)
        gemm256_k<1><<<dim3(512), 512, 131072, stream>>>(
            fctA + a * 512, 1536, ob, 512, (void*)out, 512, 0, bsum, 0);
      else
        gemm256_k<2><<<dim3(512), 512, 131072, stream>>>(
            fctA + a * 512, 1536, ob, 512, (void*)out, 512, 0, bsum, 0);
    }
  }
  if (fused) {
    // fused fc: out[c][n] = sum_a ob_all[n][a*512+k] * fctA[c][a*512+k] + bsum[c]
    // M=512 (2 bm), N=65536 (256 bn), K=1536 (NT=24), single write, no RMW
    gemm256_k<1><<<dim3(512), 512, 131072, stream>>>(
        fctA, 1536, ob, 1536, (void*)out, 1536, 0, bsum, 0);
  }
}

// Round 10
// 705.432 us; speedup vs baseline: 6.8966x; 1.1765x over previous
//
#include <hip/hip_runtime.h>
#include <stdint.h>

// ---------- types / helpers ----------
typedef __attribute__((ext_vector_type(8))) short bf16x8;   // 8 bf16 in 4 VGPRs
typedef __attribute__((ext_vector_type(4))) float f32x4;

static __device__ __forceinline__ short f2bf(float f) {
  uint32_t u = __builtin_bit_cast(uint32_t, f);
  u += 0x7fffu + ((u >> 16) & 1u);          // round-to-nearest-even
  return (short)(u >> 16);
}

static __device__ __forceinline__ void gload_lds16(const void* g, void* l) {
  __builtin_amdgcn_global_load_lds((const __attribute__((address_space(1))) void*)g,
                                   (__attribute__((address_space(3))) void*)l, 16, 0, 0);
}

#define GFENCE asm volatile("" ::: "memory")

// ---------- x transpose: (B,C,T,H,W) f32 -> xb[n][c] bf16, n = b*16384 + p ----------
__global__ __launch_bounds__(256) void transpose_x_k(const float* __restrict__ x,
                                                     short* __restrict__ xb) {
  __shared__ float t[64][65];
  const int pt = blockIdx.x, ct = blockIdx.y, b = blockIdx.z;
  const int tid = threadIdx.x;
#pragma unroll
  for (int i = 0; i < 16; i++) {
    int cc = i * 4 + (tid >> 6);
    int pp = tid & 63;
    t[cc][pp] = x[(size_t)(b * 512 + ct * 64 + cc) * 16384 + pt * 64 + pp];
  }
  __syncthreads();
#pragma unroll
  for (int i = 0; i < 2; i++) {
    int seg = i * 256 + tid;
    int pw = seg >> 3, c8 = seg & 7;
    short tmp[8];
#pragma unroll
    for (int k = 0; k < 8; k++) tmp[k] = f2bf(t[c8 * 8 + k][pw]);
    *(uint4*)&xb[(size_t)(b * 16384 + pt * 64 + pw) * 512 + ct * 64 + c8 * 8] =
        *(const uint4*)tmp;
  }
}

// ---------- weight transpose: 12x (512x512 f32 [k][n]) -> bf16 [n][k], per-dst ld ----------
struct WPtrs {
  const float* src[12];
  short* dst[12];
  int ld[12];
};

__global__ __launch_bounds__(256) void transpose_w_k(WPtrs P) {
  __shared__ float t[64][65];
  const int kt = blockIdx.x, nt = blockIdx.y, z = blockIdx.z;
  const float* src = P.src[z];
  short* dst = P.dst[z];
  const int ld = P.ld[z];
  const int tid = threadIdx.x;
#pragma unroll
  for (int i = 0; i < 16; i++) {
    int kk = i * 4 + (tid >> 6);
    int nn = tid & 63;
    t[kk][nn] = src[(kt * 64 + kk) * 512 + nt * 64 + nn];
  }
  __syncthreads();
#pragma unroll
  for (int i = 0; i < 2; i++) {
    int seg = i * 256 + tid;
    int nn = seg >> 3, k8 = seg & 7;
    short tmp[8];
#pragma unroll
    for (int k = 0; k < 8; k++) tmp[k] = f2bf(t[k8 * 8 + k][nn]);
    *(uint4*)&dst[(size_t)(nt * 64 + nn) * ld + kt * 64 + k8 * 8] = *(const uint4*)tmp;
  }
}

__global__ void bsum_k(const float* a, const float* b, const float* c, float* o) {
  int i = blockIdx.x * 256 + threadIdx.x;
  if (i < 512) o[i] = a[i] + b[i] + c[i];
}

// ---------- 256x256 8-phase GEMM (round-4/9 proven): D = A(MxK,lda)*B(NxK,ldb)^T ----------
#define LOADB(b, kh)                                                           \
  do {                                                                         \
    _Pragma("unroll") for (int ni = 0; ni < 4; ++ni) bfr[ni] =                 \
        *(const bf16x8*)(smem + ((b) * 4 + 2 + (kh)) * 16384 + boff +          \
                         ni * 1024);                                           \
  } while (0)

#define LOADA(b, kh, mq)                                                       \
  do {                                                                         \
    _Pragma("unroll") for (int mi = 0; mi < 4; ++mi) af[mi] =                  \
        *(const bf16x8*)(smem + ((b) * 4 + (kh)) * 16384 + aoff +              \
                         ((mq) * 4 + mi) * 1024);                              \
  } while (0)

#define MFMA16(mq)                                                             \
  do {                                                                         \
    __builtin_amdgcn_s_setprio(1);                                             \
    _Pragma("unroll") for (int mi = 0; mi < 4; ++mi)                           \
        _Pragma("unroll") for (int ni = 0; ni < 4; ++ni) acc[(mq) * 4 + mi]    \
            [ni] = __builtin_amdgcn_mfma_f32_16x16x32_bf16(                    \
                af[mi], bfr[ni], acc[(mq) * 4 + mi][ni], 0, 0, 0);             \
    __builtin_amdgcn_s_setprio(0);                                             \
    GFENCE;                                                                    \
  } while (0)

#define TILE(b, W0, W2, S0, S1, S2, S3)                                        \
  do {                                                                         \
    asm volatile("s_waitcnt vmcnt(" W0 ")" ::: "memory");                      \
    __builtin_amdgcn_s_barrier();                                              \
    GFENCE;                                                                    \
    LOADB(b, 0);                                                               \
    LOADA(b, 0, 0);                                                            \
    S0;                                                                        \
    MFMA16(0);                                                                 \
    __builtin_amdgcn_s_barrier();                                              \
    GFENCE;                                                                    \
    LOADA(b, 0, 1);                                                            \
    S1;                                                                        \
    MFMA16(1);                                                                 \
    asm volatile("s_waitcnt vmcnt(" W2 ")" ::: "memory");                      \
    __builtin_amdgcn_s_barrier();                                              \
    GFENCE;                                                                    \
    LOADB(b, 1);                                                               \
    LOADA(b, 1, 0);                                                            \
    S2;                                                                        \
    MFMA16(0);                                                                 \
    __builtin_amdgcn_s_barrier();                                              \
    GFENCE;                                                                    \
    LOADA(b, 1, 1);                                                            \
    S3;                                                                        \
    MFMA16(1);                                                                 \
  } while (0)

template <int MODE>
__global__ __launch_bounds__(512, 2) void gemm256_k(const short* __restrict__ A,
                                                    int lda,
                                                    const short* __restrict__ B,
                                                    int ldb, void* __restrict__ Dp,
                                                    int K, int ldd,
                                                    const float* __restrict__ bsum,
                                                    int GN) {
  extern __shared__ char smem[];
  const int tid = threadIdx.x;
  const int lane = tid & 63, wave = tid >> 6;
  const int wr = wave >> 2, wc = wave & 3;
  const int r4 = lane & 15, kl = lane >> 4;

  // bijective XCD swizzle (gridDim.x % 8 == 0 for all our grids)
  int bid = blockIdx.x;
  const int cpx = gridDim.x >> 3;
  bid = (bid & 7) * cpx + (bid >> 3);
  int bm, bn;
  if constexpr (MODE == 0) {
    bn = bid % GN;
    bm = bid / GN;
  } else {
    bm = bid & 1;
    bn = bid >> 1;
  }

  const int NT = K >> 6;

  const int srow = tid >> 2;                       // 0..127 (instr i adds 128)
  const int schk = (tid & 3) ^ ((tid >> 4) & 3);   // swizzled 16B chunk
  const short* gA0 = A + (size_t)(bm * 256 + srow) * lda + schk * 8;
  const short* gB0 = B + (size_t)(bn * 256 + srow) * ldb + schk * 8;

  auto stage = [&](int tt, int x) {  // x: 0 ALO, 1 AHI, 2 BLO, 3 BHI
    const short* g = (x < 2) ? gA0 : gB0;
    const size_t rstep = (size_t)128 * ((x < 2) ? lda : ldb);
    const size_t koff = (size_t)tt * 64 + (x & 1) * 32;
    char* ldst = smem + (((tt & 1) * 4 + x) * 16384) + wave * 1024;
#pragma unroll
    for (int i = 0; i < 2; ++i)
      gload_lds16(g + i * rstep + koff, ldst + i * 8192);
  };

  const int kls = kl ^ (r4 >> 2);
  const int aoff = wr * 8192 + r4 * 64 + kls * 16;
  const int boff = wc * 4096 + r4 * 64 + kls * 16;

  f32x4 acc[8][4];
#pragma unroll
  for (int i = 0; i < 8; ++i)
#pragma unroll
    for (int j = 0; j < 4; ++j) acc[i][j] = (f32x4){0.f, 0.f, 0.f, 0.f};
  bf16x8 af[4], bfr[4];

  stage(0, 0);
  stage(0, 2);
  stage(0, 1);
  stage(0, 3);
  stage(1, 0);
  stage(1, 2);

  int t = 0;
  for (; t < NT - 2; ++t) {
    const int b = t & 1;
    TILE(b, "8", "8", stage(t + 1, 1), stage(t + 1, 3), stage(t + 2, 0),
         stage(t + 2, 2));
  }
  {
    const int b = t & 1;  // t == NT-2
    TILE(b, "8", "8", stage(t + 1, 1), stage(t + 1, 3), (void)0, (void)0);
    ++t;
  }
  {
    const int b = t & 1;  // t == NT-1
    TILE(b, "4", "0", (void)0, (void)0, (void)0, (void)0);
  }

  const int m0 = wr * 128 + kl * 4;
  const int n0 = wc * 64 + r4;
  if (MODE == 0) {
    short* D = (short*)Dp;
#pragma unroll
    for (int mi = 0; mi < 8; ++mi)
#pragma unroll
      for (int ni = 0; ni < 4; ++ni)
#pragma unroll
        for (int r = 0; r < 4; ++r) {
          int row = bm * 256 + m0 + mi * 16 + r;
          int col = bn * 256 + n0 + ni * 16;
          D[(size_t)row * ldd + col] = f2bf(acc[mi][ni][r]);
        }
  } else {
    float* D = (float*)Dp + (size_t)((bn * 256) >> 14) * 8388608;
#pragma unroll
    for (int mi = 0; mi < 8; ++mi)
#pragma unroll
      for (int ni = 0; ni < 4; ++ni)
#pragma unroll
        for (int r = 0; r < 4; ++r) {
          int c = bm * 256 + m0 + mi * 16 + r;          // channel (M dim)
          int n = (bn * 256 + n0 + ni * 16) & 16383;    // spatial within batch
          if (MODE == 1)
            D[(size_t)c * 16384 + n] = acc[mi][ni][r] + bsum[c];
          else
            D[(size_t)c * 16384 + n] += acc[mi][ni][r];
        }
  }
}

// ---------- MFMA axial attention: one WAVE per (sequence, head) ----------
// qkv [n][1536] bf16 (Q|K|V); o [n][1536] bf16 at column obase.
// Wave-private LDS (no __syncthreads): p_lds 32x40, vt 64x40 shorts.
// S = mfma(Q-frag, K-frag) (= Q.K^T, proven GEMM convention); row softmax in f32
// via __shfl_xor over the 16-lane row group; P->bf16->LDS; O = mfma(P-frag, V^T-frag).
// L=16 zero-pads P cols / V^T rows 16..31 so the K=32 mfma is exact.
template <int L>
__global__ __launch_bounds__(256) void attn_mfma_k(const short* __restrict__ qkv,
                                                   short* __restrict__ o, int Adiv,
                                                   int Bmul, int Cmul, int stride,
                                                   int obase) {
  constexpr int MT = L / 16;            // 2 or 1 row tiles
  constexpr int PITCH = 40;             // shorts; 80B rows, 16B-aligned, 2/bank reads
  __shared__ short lds[4 * (32 + 64) * PITCH];
  const int tid = threadIdx.x;
  const int lane = tid & 63, wave = tid >> 6;
  short* p_lds = lds + wave * (96 * PITCH);
  short* vt = p_lds + 32 * PITCH;

  const int wid = blockIdx.x * 4 + wave;
  const int s = wid >> 3, head = wid & 7;
  const int base = (s / Adiv) * Bmul + (s % Adiv) * Cmul;
  const int r4 = lane & 15, kl = lane >> 4;

  if constexpr (L == 16) {  // zero padding region once (wave-private)
    for (int i = lane; i < 96 * PITCH; i += 64) p_lds[i] = 0;
  }

  // ---- Q,K fragments direct from global (A/B row-frag: row=l&15, k=(l>>4)*8)
  bf16x8 qf[MT][2], kf[MT][2];
#pragma unroll
  for (int mi = 0; mi < MT; ++mi)
#pragma unroll
    for (int ks = 0; ks < 2; ++ks) {
      size_t nrow = (size_t)(base + (mi * 16 + r4) * stride) * 1536 + head * 64 +
                    ks * 32 + kl * 8;
      qf[mi][ks] = *(const bf16x8*)&qkv[nrow];
      kf[mi][ks] = *(const bf16x8*)&qkv[nrow + 512];
    }

  // ---- V -> vt (V^T) scatter: lane loads rows j=(l>>3)+8it, cols (l&7)*8..+8
#pragma unroll
  for (int it = 0; it < L / 8; ++it) {
    int j = (lane >> 3) + it * 8;
    uint4 u = *(const uint4*)&qkv[(size_t)(base + j * stride) * 1536 + 1024 +
                                  head * 64 + (lane & 7) * 8];
    ushort e[8];
    *(uint4*)e = u;
#pragma unroll
    for (int q = 0; q < 8; ++q) vt[((lane & 7) * 8 + q) * PITCH + j] = (short)e[q];
  }

  // ---- S = Q.K^T
  f32x4 sacc[MT][MT];
#pragma unroll
  for (int i = 0; i < MT; ++i)
#pragma unroll
    for (int j = 0; j < MT; ++j) sacc[i][j] = (f32x4){0.f, 0.f, 0.f, 0.f};
#pragma unroll
  for (int mi = 0; mi < MT; ++mi)
#pragma unroll
    for (int ni = 0; ni < MT; ++ni)
#pragma unroll
      for (int ks = 0; ks < 2; ++ks)
        sacc[mi][ni] = __builtin_amdgcn_mfma_f32_16x16x32_bf16(
            qf[mi][ks], kf[ni][ks], sacc[mi][ni], 0, 0, 0);

  // ---- row softmax (rows = kl*4+reg within each mi tile; reduce over 16 col-lanes)
#pragma unroll
  for (int mi = 0; mi < MT; ++mi) {
    float mx[4], sm[4];
#pragma unroll
    for (int r = 0; r < 4; ++r) {
      float m = sacc[mi][0][r];
      if (MT == 2) m = fmaxf(m, sacc[mi][1][r]);
#pragma unroll
      for (int d = 1; d < 16; d <<= 1) m = fmaxf(m, __shfl_xor(m, d));
      mx[r] = m;
    }
#pragma unroll
    for (int ni = 0; ni < MT; ++ni)
#pragma unroll
      for (int r = 0; r < 4; ++r)
        sacc[mi][ni][r] = __expf((sacc[mi][ni][r] - mx[r]) * 0.125f);
#pragma unroll
    for (int r = 0; r < 4; ++r) {
      float t = sacc[mi][0][r];
      if (MT == 2) t += sacc[mi][1][r];
#pragma unroll
      for (int d = 1; d < 16; d <<= 1) t += __shfl_xor(t, d);
      sm[r] = 1.0f / t;
    }
    // ---- P (bf16) -> LDS [q][k]
#pragma unroll
    for (int ni = 0; ni < MT; ++ni)
#pragma unroll
      for (int r = 0; r < 4; ++r)
        p_lds[(mi * 16 + kl * 4 + r) * PITCH + ni * 16 + r4] =
            f2bf(sacc[mi][ni][r] * sm[r]);
  }
  asm volatile("s_waitcnt lgkmcnt(0)" ::: "memory");

  // ---- O = P.V via mfma(P-frag, V^T-frag), K=32 (zero-padded for L=16)
  bf16x8 paf[MT], vbf[4];
#pragma unroll
  for (int mi = 0; mi < MT; ++mi)
    paf[mi] = *(const bf16x8*)&p_lds[(mi * 16 + r4) * PITCH + kl * 8];
#pragma unroll
  for (int nd = 0; nd < 4; ++nd)
    vbf[nd] = *(const bf16x8*)&vt[(nd * 16 + r4) * PITCH + kl * 8];
  f32x4 oacc[MT][4];
#pragma unroll
  for (int i = 0; i < MT; ++i)
#pragma unroll
    for (int j = 0; j < 4; ++j) oacc[i][j] = (f32x4){0.f, 0.f, 0.f, 0.f};
#pragma unroll
  for (int mi = 0; mi < MT; ++mi)
#pragma unroll
    for (int nd = 0; nd < 4; ++nd)
      oacc[mi][nd] = __builtin_amdgcn_mfma_f32_16x16x32_bf16(paf[mi], vbf[nd],
                                                             oacc[mi][nd], 0, 0, 0);

  // ---- store O: row q = mi*16+kl*4+r, col d = nd*16+r4
#pragma unroll
  for (int mi = 0; mi < MT; ++mi)
#pragma unroll
    for (int r = 0; r < 4; ++r) {
      int n = base + (mi * 16 + kl * 4 + r) * stride;
      size_t ob = (size_t)n * 1536 + obase + head * 64 + r4;
#pragma unroll
      for (int nd = 0; nd < 4; ++nd) o[ob + nd * 16] = f2bf(oacc[mi][nd][r]);
    }
}

// ---------- launch ----------
extern "C" void kernel_launch(void* const* d_in, const int* in_sizes, int n_in,
                              void* d_out, int out_size, void* d_ws, size_t ws_size,
                              hipStream_t stream) {
  const float* x = (const float*)d_in[0];
  const float* wq[3];
  const float* wk[3];
  const float* wv[3];
  const float* fc[3];
  const float* fb[3];
  for (int a = 0; a < 3; a++) {
    wq[a] = (const float*)d_in[1 + a * 5];
    wk[a] = (const float*)d_in[2 + a * 5];
    wv[a] = (const float*)d_in[3 + a * 5];
    fc[a] = (const float*)d_in[4 + a * 5];
    fb[a] = (const float*)d_in[5 + a * 5];
  }
  char* ws = (char*)d_ws;
  short* xb = (short*)(ws);                      //  67,108,864 B
  short* qkv = (short*)(ws + 67108864);          // 201,326,592 B
  short* wqkvt = (short*)(ws + 268435456);       //   4,718,592 B (3 x 1536x512)
  short* fctA = (short*)(ws + 273154048);        //   1,572,864 B (512 x 1536)
  float* bsum = (float*)(ws + 274726912);        //       2,048 B
  short* ob = (short*)(ws + 274728960);          // 201,326,592 B (65536 x 1536)
  float* out = (float*)d_out;

  // allow 128 KiB dynamic LDS (host-side, capture-safe)
  (void)hipFuncSetAttribute((const void*)&gemm256_k<0>,
                            hipFuncAttributeMaxDynamicSharedMemorySize, 131072);
  (void)hipFuncSetAttribute((const void*)&gemm256_k<1>,
                            hipFuncAttributeMaxDynamicSharedMemorySize, 131072);

  WPtrs P;
  for (int a = 0; a < 3; a++) {
    P.src[a * 4 + 0] = wq[a];
    P.src[a * 4 + 1] = wk[a];
    P.src[a * 4 + 2] = wv[a];
    P.src[a * 4 + 3] = fc[a];
    P.dst[a * 4 + 0] = wqkvt + (size_t)a * 1536 * 512;
    P.dst[a * 4 + 1] = wqkvt + (size_t)a * 1536 * 512 + 512 * 512;
    P.dst[a * 4 + 2] = wqkvt + (size_t)a * 1536 * 512 + 2 * 512 * 512;
    P.dst[a * 4 + 3] = fctA + a * 512;   // packed [c][a*512 + k], ld 1536
    P.ld[a * 4 + 0] = 512;
    P.ld[a * 4 + 1] = 512;
    P.ld[a * 4 + 2] = 512;
    P.ld[a * 4 + 3] = 1536;
  }
  transpose_w_k<<<dim3(8, 8, 12), 256, 0, stream>>>(P);
  bsum_k<<<dim3(2), 256, 0, stream>>>(fb[0], fb[1], fb[2], bsum);
  transpose_x_k<<<dim3(256, 8, 4), 256, 0, stream>>>(x, xb);

  // per-axis attention geometry: base = (s/Adiv)*Bmul + (s%Adiv)*Cmul, rows step `stride`
  const int Ad[3] = {1, 32, 1024};
  const int Bm_[3] = {32, 1024, 16384};
  const int Cm[3] = {0, 1, 1};
  const int St[3] = {1, 32, 1024};
  const int Ls[3] = {32, 32, 16};

  for (int a = 0; a < 3; a++) {
    // QKV: M=65536 (256 bm tiles), N=1536 (6 bn tiles), K=512
    gemm256_k<0><<<dim3(1536), 512, 131072, stream>>>(
        xb, 512, wqkvt + (size_t)a * 1536 * 512, 512, (void*)qkv, 512, 1536,
        nullptr, 6);
    if (Ls[a] == 32)
      attn_mfma_k<32><<<dim3(4096), 256, 0, stream>>>(qkv, ob, Ad[a], Bm_[a], Cm[a],
                                                      St[a], a * 512);
    else
      attn_mfma_k<16><<<dim3(8192), 256, 0, stream>>>(qkv, ob, Ad[a], Bm_[a], Cm[a],
                                                      St[a], a * 512);
  }
  // fused fc: out[c][n] = sum_a ob_all[n][a*512+k] * fctA[c][a*512+k] + bsum[c]
  // M=512 (2 bm), N=65536 (256 bn), K=1536 (NT=24), single write, no RMW
  gemm256_k<1><<<dim3(512), 512, 131072, stream>>>(
      fctA, 1536, ob, 1536, (void*)out, 1536, 0, bsum, 0);
}

// Round 11
// 696.973 us; speedup vs baseline: 6.9803x; 1.0121x over previous
//
#include <hip/hip_runtime.h>
#include <stdint.h>

// ---------- types / helpers ----------
typedef __attribute__((ext_vector_type(8))) short bf16x8;   // 8 bf16 in 4 VGPRs
typedef __attribute__((ext_vector_type(4))) float f32x4;

static __device__ __forceinline__ short f2bf(float f) {
  uint32_t u = __builtin_bit_cast(uint32_t, f);
  u += 0x7fffu + ((u >> 16) & 1u);          // round-to-nearest-even
  return (short)(u >> 16);
}

static __device__ __forceinline__ void gload_lds16(const void* g, void* l) {
  __builtin_amdgcn_global_load_lds((const __attribute__((address_space(1))) void*)g,
                                   (__attribute__((address_space(3))) void*)l, 16, 0, 0);
}

#define GFENCE asm volatile("" ::: "memory")

// ---------- x transpose: (B,C,T,H,W) f32 -> xb[n][c] bf16, n = b*16384 + p ----------
__global__ __launch_bounds__(256) void transpose_x_k(const float* __restrict__ x,
                                                     short* __restrict__ xb) {
  __shared__ float t[64][65];
  const int pt = blockIdx.x, ct = blockIdx.y, b = blockIdx.z;
  const int tid = threadIdx.x;
#pragma unroll
  for (int i = 0; i < 16; i++) {
    int cc = i * 4 + (tid >> 6);
    int pp = tid & 63;
    t[cc][pp] = x[(size_t)(b * 512 + ct * 64 + cc) * 16384 + pt * 64 + pp];
  }
  __syncthreads();
#pragma unroll
  for (int i = 0; i < 2; i++) {
    int seg = i * 256 + tid;
    int pw = seg >> 3, c8 = seg & 7;
    short tmp[8];
#pragma unroll
    for (int k = 0; k < 8; k++) tmp[k] = f2bf(t[c8 * 8 + k][pw]);
    *(uint4*)&xb[(size_t)(b * 16384 + pt * 64 + pw) * 512 + ct * 64 + c8 * 8] =
        *(const uint4*)tmp;
  }
}

// ---------- weight transpose: 12x (512x512 f32 [k][n]) -> bf16 [n][k], per-dst ld ----------
struct WPtrs {
  const float* src[12];
  short* dst[12];
  int ld[12];
};

__global__ __launch_bounds__(256) void transpose_w_k(WPtrs P) {
  __shared__ float t[64][65];
  const int kt = blockIdx.x, nt = blockIdx.y, z = blockIdx.z;
  const float* src = P.src[z];
  short* dst = P.dst[z];
  const int ld = P.ld[z];
  const int tid = threadIdx.x;
#pragma unroll
  for (int i = 0; i < 16; i++) {
    int kk = i * 4 + (tid >> 6);
    int nn = tid & 63;
    t[kk][nn] = src[(kt * 64 + kk) * 512 + nt * 64 + nn];
  }
  __syncthreads();
#pragma unroll
  for (int i = 0; i < 2; i++) {
    int seg = i * 256 + tid;
    int nn = seg >> 3, k8 = seg & 7;
    short tmp[8];
#pragma unroll
    for (int k = 0; k < 8; k++) tmp[k] = f2bf(t[k8 * 8 + k][nn]);
    *(uint4*)&dst[(size_t)(nt * 64 + nn) * ld + kt * 64 + k8 * 8] = *(const uint4*)tmp;
  }
}

__global__ void bsum_k(const float* a, const float* b, const float* c, float* o) {
  int i = blockIdx.x * 256 + threadIdx.x;
  if (i < 512) o[i] = a[i] + b[i] + c[i];
}

// ---------- 256x256 read-ahead 8-phase GEMM: D = A(MxK,lda)*B(NxK,ldb)^T ----------
// m201-faithful micro-texture: each phase issues the NEXT phase's ds_reads
// (ping-pong frag regs afA/afB, bfA/bfB), so MFMA never waits on same-phase LDS.
// LDS: 2 buffers x {ALO,AHI,BLO,BHI}, 16 KB each (round-4/9 layout+swizzle).
// Phase slot = [vmcnt?][barrier][reads p+1][stage][MFMA p].
// Reads: P0->A(kh0,mq1); P1->B(kh1)+A(kh1,mq0); P2->A(kh1,mq1); P3->B,A(kh0,t+1).
// Stages: P0:AHI(t+1) P1:BHI(t+1) P2:ALO(t+2) P3:BLO(t+2) (2 gload_lds each).
// vmcnt ledger (per-thread): steady waits vmcnt(6) @P1 (retire AHI/BHI t) and
// @P3 (retire ALO/BLO t+1); prologue 8; tail (NT-2): 6/4; (NT-1): 0/0.
// MODE 0: D bf16 [M][ldd].  MODE 1: D f32 out (B,C,THW) = v + bsum[c].
#define READ_B(DST, b, kh)                                                     \
  do {                                                                         \
    _Pragma("unroll") for (int ni = 0; ni < 4; ++ni) DST[ni] =                 \
        *(const bf16x8*)(smem + ((b) * 4 + 2 + (kh)) * 16384 + boff +          \
                         ni * 1024);                                           \
  } while (0)

#define READ_A(DST, b, kh, mq)                                                 \
  do {                                                                         \
    _Pragma("unroll") for (int mi = 0; mi < 4; ++mi) DST[mi] =                 \
        *(const bf16x8*)(smem + ((b) * 4 + (kh)) * 16384 + aoff +              \
                         ((mq) * 4 + mi) * 1024);                              \
  } while (0)

#define MFMAX(mq, AF, BF)                                                      \
  do {                                                                         \
    __builtin_amdgcn_s_setprio(1);                                             \
    _Pragma("unroll") for (int mi = 0; mi < 4; ++mi)                           \
        _Pragma("unroll") for (int ni = 0; ni < 4; ++ni) acc[(mq) * 4 + mi]    \
            [ni] = __builtin_amdgcn_mfma_f32_16x16x32_bf16(                    \
                AF[mi], BF[ni], acc[(mq) * 4 + mi][ni], 0, 0, 0);              \
    __builtin_amdgcn_s_setprio(0);                                             \
    GFENCE;                                                                    \
  } while (0)

#define TILE_RA(b, b2, W1, W3, S0, S1, S2, S3, RA)                             \
  do {                                                                         \
    /* P0: mfma(kh0,mq0) on afA,bfA; read A(kh0,mq1) */                        \
    __builtin_amdgcn_s_barrier();                                              \
    GFENCE;                                                                    \
    READ_A(afB, b, 0, 1);                                                      \
    S0;                                                                        \
    GFENCE;                                                                    \
    MFMAX(0, afA, bfA);                                                        \
    /* P1: mfma(kh0,mq1) on afB,bfA; read B(kh1)+A(kh1,mq0) */                 \
    asm volatile("s_waitcnt vmcnt(" W1 ")" ::: "memory");                      \
    __builtin_amdgcn_s_barrier();                                              \
    GFENCE;                                                                    \
    READ_B(bfB, b, 1);                                                         \
    READ_A(afA, b, 1, 0);                                                      \
    S1;                                                                        \
    GFENCE;                                                                    \
    MFMAX(1, afB, bfA);                                                        \
    /* P2: mfma(kh1,mq0) on afA,bfB; read A(kh1,mq1) */                        \
    __builtin_amdgcn_s_barrier();                                              \
    GFENCE;                                                                    \
    READ_A(afB, b, 1, 1);                                                      \
    S2;                                                                        \
    GFENCE;                                                                    \
    MFMAX(0, afA, bfB);                                                        \
    /* P3: mfma(kh1,mq1) on afB,bfB; read B,A(kh0) of next tile */             \
    asm volatile("s_waitcnt vmcnt(" W3 ")" ::: "memory");                      \
    __builtin_amdgcn_s_barrier();                                              \
    GFENCE;                                                                    \
    RA;                                                                        \
    S3;                                                                        \
    GFENCE;                                                                    \
    MFMAX(1, afB, bfB);                                                        \
  } while (0)

template <int MODE>
__global__ __launch_bounds__(512, 2) void gemm256_k(const short* __restrict__ A,
                                                    int lda,
                                                    const short* __restrict__ B,
                                                    int ldb, void* __restrict__ Dp,
                                                    int K, int ldd,
                                                    const float* __restrict__ bsum,
                                                    int GN) {
  extern __shared__ char smem[];
  const int tid = threadIdx.x;
  const int lane = tid & 63, wave = tid >> 6;
  const int wr = wave >> 2, wc = wave & 3;
  const int r4 = lane & 15, kl = lane >> 4;

  // bijective XCD swizzle (gridDim.x % 8 == 0 for all our grids)
  int bid = blockIdx.x;
  const int cpx = gridDim.x >> 3;
  bid = (bid & 7) * cpx + (bid >> 3);
  int bm, bn;
  if constexpr (MODE == 0) {
    bn = bid % GN;
    bm = bid / GN;
  } else {
    bm = bid & 1;
    bn = bid >> 1;
  }

  const int NT = K >> 6;

  const int srow = tid >> 2;                       // 0..127 (instr i adds 128)
  const int schk = (tid & 3) ^ ((tid >> 4) & 3);   // swizzled 16B chunk
  const short* gA0 = A + (size_t)(bm * 256 + srow) * lda + schk * 8;
  const short* gB0 = B + (size_t)(bn * 256 + srow) * ldb + schk * 8;

  auto stage = [&](int tt, int x) {  // x: 0 ALO, 1 AHI, 2 BLO, 3 BHI
    const short* g = (x < 2) ? gA0 : gB0;
    const size_t rstep = (size_t)128 * ((x < 2) ? lda : ldb);
    const size_t koff = (size_t)tt * 64 + (x & 1) * 32;
    char* ldst = smem + (((tt & 1) * 4 + x) * 16384) + wave * 1024;
#pragma unroll
    for (int i = 0; i < 2; ++i)
      gload_lds16(g + i * rstep + koff, ldst + i * 8192);
  };

  const int kls = kl ^ (r4 >> 2);
  const int aoff = wr * 8192 + r4 * 64 + kls * 16;
  const int boff = wc * 4096 + r4 * 64 + kls * 16;

  f32x4 acc[8][4];
#pragma unroll
  for (int i = 0; i < 8; ++i)
#pragma unroll
    for (int j = 0; j < 4; ++j) acc[i][j] = (f32x4){0.f, 0.f, 0.f, 0.f};
  bf16x8 afA[4], afB[4], bfA[4], bfB[4];

  // prologue: ALO0 BLO0 AHI0 BHI0 ALO1 BLO1 (12 loads); retire ALO0,BLO0;
  // then pre-issue tile0 kh0 fragments (consumed by P0(0)).
  stage(0, 0);
  stage(0, 2);
  stage(0, 1);
  stage(0, 3);
  stage(1, 0);
  stage(1, 2);
  asm volatile("s_waitcnt vmcnt(8)" ::: "memory");
  __builtin_amdgcn_s_barrier();
  GFENCE;
  READ_B(bfA, 0, 0);
  READ_A(afA, 0, 0, 0);
  GFENCE;

  int t = 0;
  for (; t < NT - 2; ++t) {
    const int b = t & 1, b2 = b ^ 1;
    TILE_RA(b, b2, "6", "6", stage(t + 1, 1), stage(t + 1, 3), stage(t + 2, 0),
            stage(t + 2, 2), {
              READ_B(bfA, b2, 0);
              READ_A(afA, b2, 0, 0);
            });
  }
  {
    const int b = t & 1, b2 = b ^ 1;  // t == NT-2: hi stages only; RA for last tile
    TILE_RA(b, b2, "6", "4", stage(t + 1, 1), stage(t + 1, 3), (void)0, (void)0, {
      READ_B(bfA, b2, 0);
      READ_A(afA, b2, 0, 0);
    });
    ++t;
  }
  {
    const int b = t & 1, b2 = b ^ 1;  // t == NT-1: no stages, no read-ahead
    TILE_RA(b, b2, "0", "0", (void)0, (void)0, (void)0, (void)0, (void)0);
  }

  // ---- epilogue
  const int m0 = wr * 128 + kl * 4;
  const int n0 = wc * 64 + r4;
  if (MODE == 0) {
    short* D = (short*)Dp;
#pragma unroll
    for (int mi = 0; mi < 8; ++mi)
#pragma unroll
      for (int ni = 0; ni < 4; ++ni)
#pragma unroll
        for (int r = 0; r < 4; ++r) {
          int row = bm * 256 + m0 + mi * 16 + r;
          int col = bn * 256 + n0 + ni * 16;
          D[(size_t)row * ldd + col] = f2bf(acc[mi][ni][r]);
        }
  } else {
    float* D = (float*)Dp + (size_t)((bn * 256) >> 14) * 8388608;
#pragma unroll
    for (int mi = 0; mi < 8; ++mi)
#pragma unroll
      for (int ni = 0; ni < 4; ++ni)
#pragma unroll
        for (int r = 0; r < 4; ++r) {
          int c = bm * 256 + m0 + mi * 16 + r;          // channel (M dim)
          int n = (bn * 256 + n0 + ni * 16) & 16383;    // spatial within batch
          D[(size_t)c * 16384 + n] = acc[mi][ni][r] + bsum[c];
        }
  }
}

// ---------- MFMA axial attention: one WAVE per (sequence, head) ----------
// (round-10 proven) qkv [n][1536] bf16; o [n][1536] bf16 at column obase.
template <int L>
__global__ __launch_bounds__(256) void attn_mfma_k(const short* __restrict__ qkv,
                                                   short* __restrict__ o, int Adiv,
                                                   int Bmul, int Cmul, int stride,
                                                   int obase) {
  constexpr int MT = L / 16;            // 2 or 1 row tiles
  constexpr int PITCH = 40;             // shorts; 80B rows
  __shared__ short lds[4 * (32 + 64) * PITCH];
  const int tid = threadIdx.x;
  const int lane = tid & 63, wave = tid >> 6;
  short* p_lds = lds + wave * (96 * PITCH);
  short* vt = p_lds + 32 * PITCH;

  const int wid = blockIdx.x * 4 + wave;
  const int s = wid >> 3, head = wid & 7;
  const int base = (s / Adiv) * Bmul + (s % Adiv) * Cmul;
  const int r4 = lane & 15, kl = lane >> 4;

  if constexpr (L == 16) {
    for (int i = lane; i < 96 * PITCH; i += 64) p_lds[i] = 0;
  }

  bf16x8 qf[MT][2], kf[MT][2];
#pragma unroll
  for (int mi = 0; mi < MT; ++mi)
#pragma unroll
    for (int ks = 0; ks < 2; ++ks) {
      size_t nrow = (size_t)(base + (mi * 16 + r4) * stride) * 1536 + head * 64 +
                    ks * 32 + kl * 8;
      qf[mi][ks] = *(const bf16x8*)&qkv[nrow];
      kf[mi][ks] = *(const bf16x8*)&qkv[nrow + 512];
    }

#pragma unroll
  for (int it = 0; it < L / 8; ++it) {
    int j = (lane >> 3) + it * 8;
    uint4 u = *(const uint4*)&qkv[(size_t)(base + j * stride) * 1536 + 1024 +
                                  head * 64 + (lane & 7) * 8];
    ushort e[8];
    *(uint4*)e = u;
#pragma unroll
    for (int q = 0; q < 8; ++q) vt[((lane & 7) * 8 + q) * PITCH + j] = (short)e[q];
  }

  f32x4 sacc[MT][MT];
#pragma unroll
  for (int i = 0; i < MT; ++i)
#pragma unroll
    for (int j = 0; j < MT; ++j) sacc[i][j] = (f32x4){0.f, 0.f, 0.f, 0.f};
#pragma unroll
  for (int mi = 0; mi < MT; ++mi)
#pragma unroll
    for (int ni = 0; ni < MT; ++ni)
#pragma unroll
      for (int ks = 0; ks < 2; ++ks)
        sacc[mi][ni] = __builtin_amdgcn_mfma_f32_16x16x32_bf16(
            qf[mi][ks], kf[ni][ks], sacc[mi][ni], 0, 0, 0);

#pragma unroll
  for (int mi = 0; mi < MT; ++mi) {
    float mx[4], sm[4];
#pragma unroll
    for (int r = 0; r < 4; ++r) {
      float m = sacc[mi][0][r];
      if (MT == 2) m = fmaxf(m, sacc[mi][1][r]);
#pragma unroll
      for (int d = 1; d < 16; d <<= 1) m = fmaxf(m, __shfl_xor(m, d));
      mx[r] = m;
    }
#pragma unroll
    for (int ni = 0; ni < MT; ++ni)
#pragma unroll
      for (int r = 0; r < 4; ++r)
        sacc[mi][ni][r] = __expf((sacc[mi][ni][r] - mx[r]) * 0.125f);
#pragma unroll
    for (int r = 0; r < 4; ++r) {
      float t = sacc[mi][0][r];
      if (MT == 2) t += sacc[mi][1][r];
#pragma unroll
      for (int d = 1; d < 16; d <<= 1) t += __shfl_xor(t, d);
      sm[r] = 1.0f / t;
    }
#pragma unroll
    for (int ni = 0; ni < MT; ++ni)
#pragma unroll
      for (int r = 0; r < 4; ++r)
        p_lds[(mi * 16 + kl * 4 + r) * PITCH + ni * 16 + r4] =
            f2bf(sacc[mi][ni][r] * sm[r]);
  }
  asm volatile("s_waitcnt lgkmcnt(0)" ::: "memory");

  bf16x8 paf[MT], vbf[4];
#pragma unroll
  for (int mi = 0; mi < MT; ++mi)
    paf[mi] = *(const bf16x8*)&p_lds[(mi * 16 + r4) * PITCH + kl * 8];
#pragma unroll
  for (int nd = 0; nd < 4; ++nd)
    vbf[nd] = *(const bf16x8*)&vt[(nd * 16 + r4) * PITCH + kl * 8];
  f32x4 oacc[MT][4];
#pragma unroll
  for (int i = 0; i < MT; ++i)
#pragma unroll
    for (int j = 0; j < 4; ++j) oacc[i][j] = (f32x4){0.f, 0.f, 0.f, 0.f};
#pragma unroll
  for (int mi = 0; mi < MT; ++mi)
#pragma unroll
    for (int nd = 0; nd < 4; ++nd)
      oacc[mi][nd] = __builtin_amdgcn_mfma_f32_16x16x32_bf16(paf[mi], vbf[nd],
                                                             oacc[mi][nd], 0, 0, 0);

#pragma unroll
  for (int mi = 0; mi < MT; ++mi)
#pragma unroll
    for (int r = 0; r < 4; ++r) {
      int n = base + (mi * 16 + kl * 4 + r) * stride;
      size_t ob = (size_t)n * 1536 + obase + head * 64 + r4;
#pragma unroll
      for (int nd = 0; nd < 4; ++nd) o[ob + nd * 16] = f2bf(oacc[mi][nd][r]);
    }
}

// ---------- launch ----------
extern "C" void kernel_launch(void* const* d_in, const int* in_sizes, int n_in,
                              void* d_out, int out_size, void* d_ws, size_t ws_size,
                              hipStream_t stream) {
  const float* x = (const float*)d_in[0];
  const float* wq[3];
  const float* wk[3];
  const float* wv[3];
  const float* fc[3];
  const float* fb[3];
  for (int a = 0; a < 3; a++) {
    wq[a] = (const float*)d_in[1 + a * 5];
    wk[a] = (const float*)d_in[2 + a * 5];
    wv[a] = (const float*)d_in[3 + a * 5];
    fc[a] = (const float*)d_in[4 + a * 5];
    fb[a] = (const float*)d_in[5 + a * 5];
  }
  char* ws = (char*)d_ws;
  short* xb = (short*)(ws);                      //  67,108,864 B
  short* qkv = (short*)(ws + 67108864);          // 201,326,592 B
  short* wqkvt = (short*)(ws + 268435456);       //   4,718,592 B (3 x 1536x512)
  short* fctA = (short*)(ws + 273154048);        //   1,572,864 B (512 x 1536)
  float* bsum = (float*)(ws + 274726912);        //       2,048 B
  short* ob = (short*)(ws + 274728960);          // 201,326,592 B (65536 x 1536)
  float* out = (float*)d_out;

  // allow 128 KiB dynamic LDS (host-side, capture-safe)
  (void)hipFuncSetAttribute((const void*)&gemm256_k<0>,
                            hipFuncAttributeMaxDynamicSharedMemorySize, 131072);
  (void)hipFuncSetAttribute((const void*)&gemm256_k<1>,
                            hipFuncAttributeMaxDynamicSharedMemorySize, 131072);

  WPtrs P;
  for (int a = 0; a < 3; a++) {
    P.src[a * 4 + 0] = wq[a];
    P.src[a * 4 + 1] = wk[a];
    P.src[a * 4 + 2] = wv[a];
    P.src[a * 4 + 3] = fc[a];
    P.dst[a * 4 + 0] = wqkvt + (size_t)a * 1536 * 512;
    P.dst[a * 4 + 1] = wqkvt + (size_t)a * 1536 * 512 + 512 * 512;
    P.dst[a * 4 + 2] = wqkvt + (size_t)a * 1536 * 512 + 2 * 512 * 512;
    P.dst[a * 4 + 3] = fctA + a * 512;   // packed [c][a*512 + k], ld 1536
    P.ld[a * 4 + 0] = 512;
    P.ld[a * 4 + 1] = 512;
    P.ld[a * 4 + 2] = 512;
    P.ld[a * 4 + 3] = 1536;
  }
  transpose_w_k<<<dim3(8, 8, 12), 256, 0, stream>>>(P);
  bsum_k<<<dim3(2), 256, 0, stream>>>(fb[0], fb[1], fb[2], bsum);
  transpose_x_k<<<dim3(256, 8, 4), 256, 0, stream>>>(x, xb);

  // per-axis attention geometry: base = (s/Adiv)*Bmul + (s%Adiv)*Cmul, rows step `stride`
  const int Ad[3] = {1, 32, 1024};
  const int Bm_[3] = {32, 1024, 16384};
  const int Cm[3] = {0, 1, 1};
  const int St[3] = {1, 32, 1024};
  const int Ls[3] = {32, 32, 16};

  for (int a = 0; a < 3; a++) {
    // QKV: M=65536 (256 bm tiles), N=1536 (6 bn tiles), K=512 (NT=8)
    gemm256_k<0><<<dim3(1536), 512, 131072, stream>>>(
        xb, 512, wqkvt + (size_t)a * 1536 * 512, 512, (void*)qkv, 512, 1536,
        nullptr, 6);
    if (Ls[a] == 32)
      attn_mfma_k<32><<<dim3(4096), 256, 0, stream>>>(qkv, ob, Ad[a], Bm_[a], Cm[a],
                                                      St[a], a * 512);
    else
      attn_mfma_k<16><<<dim3(8192), 256, 0, stream>>>(qkv, ob, Ad[a], Bm_[a], Cm[a],
                                                      St[a], a * 512);
  }
  // fused fc: out[c][n] = sum_a ob_all[n][a*512+k] * fctA[c][a*512+k] + bsum[c]
  // M=512 (2 bm), N=65536 (256 bn), K=1536 (NT=24), single write, no RMW
  gemm256_k<1><<<dim3(512), 512, 131072, stream>>>(
      fctA, 1536, ob, 1536, (void*)out, 1536, 0, bsum, 0);
}